// Round 1
// baseline (5453.108 us; speedup 1.0000x reference)
//
#include <hip/hip_runtime.h>
#include <cstdint>
#include <cstddef>

typedef _Float16 f16;
typedef _Float16 f16x2 __attribute__((ext_vector_type(2)));
typedef _Float16 f16x4 __attribute__((ext_vector_type(4)));
typedef _Float16 f16x8 __attribute__((ext_vector_type(8)));

#define S_LEN 2048
#define BATCH 64
#define I_DIM 128
#define H_DIM 512
#define O_DIM 64

// v_dot2_f32_f16: 2 f16 MACs, fp32 accumulate. CK-standard intrinsic on CDNA.
__device__ __forceinline__ float fdot2f(f16x2 a, f16x2 b, float c) {
#if __has_builtin(__builtin_amdgcn_fdot2)
    return __builtin_amdgcn_fdot2(a, b, c, false);
#else
    return c + (float)a.x * (float)b.x + (float)a.y * (float)b.y;
#endif
}

// ---------------------------------------------------------------------------
// Phase 1: u[row][c] = sum_k x[row][k] * Wih[k][c], rows = B*S, K=128, N=512.
// f16 inputs (converted in LDS), fp32 accumulate, f16 output into ws.
// Tile: 32 rows x 128 cols per 256-thread WG. LDS: 32KB Wih pairs + 8KB x.
// ---------------------------------------------------------------------------
__global__ __launch_bounds__(256)
void u_gemm_kernel(const float* __restrict__ x, const float* __restrict__ Wih,
                   f16* __restrict__ u) {
    const int tid = threadIdx.x;
    const int r0 = blockIdx.x * 32;
    const int c0 = blockIdx.y * 128;

    __shared__ __align__(16) f16x2 wih_s[I_DIM / 2][128];  // [kp][c] pairs over k
    __shared__ __align__(16) f16x2 x_s[32][I_DIM / 2];     // [r][kp]

#pragma unroll
    for (int i = 0; i < 32; ++i) {
        int idx = i * 256 + tid;          // 0..8191
        int kp = idx >> 7;
        int cl = idx & 127;
        float w0 = Wih[(size_t)(2 * kp + 0) * H_DIM + c0 + cl];
        float w1 = Wih[(size_t)(2 * kp + 1) * H_DIM + c0 + cl];
        f16x2 w; w.x = (f16)w0; w.y = (f16)w1;
        wih_s[kp][cl] = w;
    }
    // x tile: 32*128 consecutive floats
    const float4* xs = (const float4*)(x + (size_t)r0 * I_DIM);
    f16x4* xd = (f16x4*)x_s;
#pragma unroll
    for (int i = 0; i < 4; ++i) {
        int idx = i * 256 + tid;          // 0..1023 float4s
        float4 v = xs[idx];
        f16x4 h; h.x = (f16)v.x; h.y = (f16)v.y; h.z = (f16)v.z; h.w = (f16)v.w;
        xd[idx] = h;
    }
    __syncthreads();

    const int cl = tid & 127;
    const int rh = tid >> 7;              // 0..1 -> rows rh*16..rh*16+15
    float acc[16];
#pragma unroll
    for (int r = 0; r < 16; ++r) acc[r] = 0.f;

#pragma unroll
    for (int kc = 0; kc < 2; ++kc) {
        f16x2 wv[32];
#pragma unroll
        for (int i = 0; i < 32; ++i) wv[i] = wih_s[kc * 32 + i][cl];
#pragma unroll
        for (int r = 0; r < 16; ++r) {
            const int row = rh * 16 + r;
#pragma unroll
            for (int m = 0; m < 8; ++m) {
                f16x8 h8 = *(const f16x8*)(&x_s[row][kc * 32 + 4 * m]);
                const f16x2* hp = (const f16x2*)&h8;
                acc[r] = fdot2f(wv[4 * m + 0], hp[0], acc[r]);
                acc[r] = fdot2f(wv[4 * m + 1], hp[1], acc[r]);
                acc[r] = fdot2f(wv[4 * m + 2], hp[2], acc[r]);
                acc[r] = fdot2f(wv[4 * m + 3], hp[3], acc[r]);
            }
        }
    }
#pragma unroll
    for (int r = 0; r < 16; ++r) {
        int row = r0 + rh * 16 + r;
        u[(size_t)row * H_DIM + c0 + cl] = (f16)acc[r];
    }
}

// ---------------------------------------------------------------------------
// Phase 2: the sequential scan. One WG (512 threads) per batch element.
// Thread j owns column j of W_rec: 456 entries in VGPRs (228 f16 pairs),
// 56-entry tail in LDS (7 groups of 8, b128-read). h double-buffered in LDS
// as f16 pairs (broadcast reads). h_prev kept fp32 in-register. u is read
// from ws and the slot is overwritten with hs[t] (in-place, same thread).
// One __syncthreads per step.
// ---------------------------------------------------------------------------
#define REG_PAIRS 228          // pairs 0..227 -> k = 0..455 in VGPRs
#define LDS_GROUPS 7           // pairs 228..255 -> k = 456..511 in LDS

__global__ __launch_bounds__(512, 2)
void rnn_scan_kernel(const float* __restrict__ Wrec, f16* __restrict__ uhs) {
    const int j = threadIdx.x;   // hidden column
    const int b = blockIdx.x;    // batch element

    __shared__ __align__(16) f16x2 h_buf[2][H_DIM / 2];        // 2 KB
    __shared__ __align__(16) f16x8 w_lds[LDS_GROUPS][H_DIM];   // 57344 B
    // total LDS 59392 B < 64 KB

    // Load W_rec column j. Coalesced per k (consecutive j -> consecutive addr).
    f16x2 wreg[REG_PAIRS];
#pragma unroll
    for (int p = 0; p < REG_PAIRS; ++p) {
        float w0 = Wrec[(size_t)(2 * p + 0) * H_DIM + j];
        float w1 = Wrec[(size_t)(2 * p + 1) * H_DIM + j];
        f16x2 w; w.x = (f16)w0; w.y = (f16)w1;
        wreg[p] = w;
    }
#pragma unroll
    for (int g = 0; g < LDS_GROUPS; ++g) {
        f16x8 v;
#pragma unroll
        for (int e = 0; e < 8; ++e)
            v[e] = (f16)Wrec[(size_t)(2 * REG_PAIRS + g * 8 + e) * H_DIM + j];
        w_lds[g][j] = v;       // (g*512 + j)*16 bytes: conflict-free
    }
    if (j < H_DIM / 2) {
        f16x2 z; z.x = (f16)0.f; z.y = (f16)0.f;
        h_buf[0][j] = z;       // h0 = 0
    }
    __syncthreads();

    f16* io = uhs + (size_t)b * S_LEN * H_DIM + j;
    float h_prev = 0.f;
    float u_cur = (float)io[0];

    for (int t = 0; t < S_LEN; ++t) {
        // prefetch next u (issued early; no dependency until loop end)
        f16 u_next = (f16)0.f;
        if (t + 1 < S_LEN) u_next = io[(t + 1) * H_DIM];

        const f16x2* hb = h_buf[t & 1];
        float acc = 0.f;
#pragma unroll
        for (int c = 0; c < REG_PAIRS / 4; ++c) {      // 57 iters
            f16x8 h8 = *(const f16x8*)(hb + 4 * c);    // broadcast b128: 4 h-pairs
            const f16x2* hp = (const f16x2*)&h8;
            acc = fdot2f(wreg[4 * c + 0], hp[0], acc);
            acc = fdot2f(wreg[4 * c + 1], hp[1], acc);
            acc = fdot2f(wreg[4 * c + 2], hp[2], acc);
            acc = fdot2f(wreg[4 * c + 3], hp[3], acc);
        }
#pragma unroll
        for (int g = 0; g < LDS_GROUPS; ++g) {         // tail k=456..511
            f16x8 h8 = *(const f16x8*)(hb + REG_PAIRS + 4 * g);
            f16x8 w8 = w_lds[g][j];
            const f16x2* hp = (const f16x2*)&h8;
            const f16x2* wp = (const f16x2*)&w8;
            acc = fdot2f(wp[0], hp[0], acc);
            acc = fdot2f(wp[1], hp[1], acc);
            acc = fdot2f(wp[2], hp[2], acc);
            acc = fdot2f(wp[3], hp[3], acc);
        }
        float z = acc + u_cur;
        // tanh(z) = 1 - 2/(exp(2z)+1); saturates correctly at +/-inf
        float e2 = __expf(2.f * z);
        float r = 1.f - 2.f / (e2 + 1.f);
        float hn = 0.8f * h_prev + 0.2f * r;
        h_prev = hn;
        f16 hh = (f16)hn;
        ((f16*)h_buf[(t + 1) & 1])[j] = hh;   // next step's input
        io[t * H_DIM] = hh;                   // hs[b][t][j] overwrites u slot
        u_cur = (float)u_next;
        __syncthreads();                      // writes visible before next read
    }
}

// ---------------------------------------------------------------------------
// Phase 3: out[row][o] = sum_k hs[row][k] * Who[k][o], K=512, O=64, fp32 out.
// Tile: 32 rows per WG, K split in 2 chunks of 256. LDS: 32KB Who + 16KB hs.
// ---------------------------------------------------------------------------
__global__ __launch_bounds__(256)
void out_gemm_kernel(const f16* __restrict__ hs, const float* __restrict__ Who,
                     float* __restrict__ out) {
    const int tid = threadIdx.x;
    const int r0 = blockIdx.x * 32;

    __shared__ __align__(16) f16x2 who_s[128][O_DIM];   // [kp][o] pairs over k
    __shared__ __align__(16) f16x2 hs_s[32][128];       // [r][kp]

    const int o = tid & 63;
    const int rg = tid >> 6;    // 0..3 -> rows rg*8..rg*8+7

    float acc[8];
#pragma unroll
    for (int r = 0; r < 8; ++r) acc[r] = 0.f;

    for (int kc = 0; kc < 2; ++kc) {
        if (kc) __syncthreads();   // protect LDS reuse across chunks
#pragma unroll
        for (int i = 0; i < 32; ++i) {
            int idx = i * 256 + tid;   // 0..8191
            int kp = idx >> 6;
            int oc = idx & 63;
            float w0 = Who[(size_t)(kc * 256 + 2 * kp + 0) * O_DIM + oc];
            float w1 = Who[(size_t)(kc * 256 + 2 * kp + 1) * O_DIM + oc];
            f16x2 w; w.x = (f16)w0; w.y = (f16)w1;
            who_s[kp][oc] = w;
        }
        f16x8* hd = (f16x8*)hs_s;
#pragma unroll
        for (int i = 0; i < 4; ++i) {
            int idx = i * 256 + tid;   // 0..1023 f16x8
            int r = idx >> 5;
            int m = idx & 31;
            f16x8 v = *(const f16x8*)(hs + (size_t)(r0 + r) * H_DIM + kc * 256 + m * 8);
            hd[idx] = v;
        }
        __syncthreads();

#pragma unroll
        for (int sc = 0; sc < 4; ++sc) {
            f16x2 wv[32];
#pragma unroll
            for (int i = 0; i < 32; ++i) wv[i] = who_s[sc * 32 + i][o];
#pragma unroll
            for (int r = 0; r < 8; ++r) {
                const int row = rg * 8 + r;
#pragma unroll
                for (int m = 0; m < 8; ++m) {
                    f16x8 h8 = *(const f16x8*)(&hs_s[row][sc * 32 + 4 * m]);
                    const f16x2* hp = (const f16x2*)&h8;
                    acc[r] = fdot2f(wv[4 * m + 0], hp[0], acc[r]);
                    acc[r] = fdot2f(wv[4 * m + 1], hp[1], acc[r]);
                    acc[r] = fdot2f(wv[4 * m + 2], hp[2], acc[r]);
                    acc[r] = fdot2f(wv[4 * m + 3], hp[3], acc[r]);
                }
            }
        }
    }
#pragma unroll
    for (int r = 0; r < 8; ++r) {
        int row = r0 + rg * 8 + r;
        out[(size_t)row * O_DIM + o] = acc[r];
    }
}

extern "C" void kernel_launch(void* const* d_in, const int* in_sizes, int n_in,
                              void* d_out, int out_size, void* d_ws, size_t ws_size,
                              hipStream_t stream) {
    const float* x    = (const float*)d_in[0];   // [64][2048][128]
    const float* Wih  = (const float*)d_in[1];   // [128][512]
    const float* Wrec = (const float*)d_in[2];   // [512][512]
    const float* Who  = (const float*)d_in[3];   // [512][64]
    float* out = (float*)d_out;                  // [64][2048][64]
    f16* uhs = (f16*)d_ws;                       // 64*2048*512 f16 = 128 MB (u, then hs in-place)

    const int R = BATCH * S_LEN;                 // 131072 rows

    u_gemm_kernel<<<dim3(R / 32, H_DIM / 128), 256, 0, stream>>>(x, Wih, uhs);
    rnn_scan_kernel<<<dim3(BATCH), 512, 0, stream>>>(Wrec, uhs);
    out_gemm_kernel<<<dim3(R / 32), 256, 0, stream>>>(uhs, Who, out);
}

// Round 2
// 3541.225 us; speedup vs baseline: 1.5399x; 1.5399x over previous
//
#include <hip/hip_runtime.h>
#include <cstdint>
#include <cstddef>

typedef _Float16 f16;
typedef _Float16 f16x2 __attribute__((ext_vector_type(2)));
typedef _Float16 f16x4 __attribute__((ext_vector_type(4)));
typedef _Float16 f16x8 __attribute__((ext_vector_type(8)));

#define S_LEN 2048
#define BATCH 64
#define I_DIM 128
#define H_DIM 512
#define O_DIM 64

// v_dot2_f32_f16: 2 f16 MACs, fp32 accumulate.
__device__ __forceinline__ float fdot2f(f16x2 a, f16x2 b, float c) {
#if __has_builtin(__builtin_amdgcn_fdot2)
    return __builtin_amdgcn_fdot2(a, b, c, false);
#else
    return c + (float)a.x * (float)b.x + (float)a.y * (float)b.y;
#endif
}

// ---------------------------------------------------------------------------
// Phase 1: u[row][c] = sum_k x[row][k] * Wih[k][c], rows = B*S, K=128, N=512.
// ---------------------------------------------------------------------------
__global__ __launch_bounds__(256)
void u_gemm_kernel(const float* __restrict__ x, const float* __restrict__ Wih,
                   f16* __restrict__ u) {
    const int tid = threadIdx.x;
    const int r0 = blockIdx.x * 32;
    const int c0 = blockIdx.y * 128;

    __shared__ __align__(16) f16x2 wih_s[I_DIM / 2][128];
    __shared__ __align__(16) f16x2 x_s[32][I_DIM / 2];

#pragma unroll
    for (int i = 0; i < 32; ++i) {
        int idx = i * 256 + tid;
        int kp = idx >> 7;
        int cl = idx & 127;
        float w0 = Wih[(size_t)(2 * kp + 0) * H_DIM + c0 + cl];
        float w1 = Wih[(size_t)(2 * kp + 1) * H_DIM + c0 + cl];
        f16x2 w; w.x = (f16)w0; w.y = (f16)w1;
        wih_s[kp][cl] = w;
    }
    const float4* xs = (const float4*)(x + (size_t)r0 * I_DIM);
    f16x4* xd = (f16x4*)x_s;
#pragma unroll
    for (int i = 0; i < 4; ++i) {
        int idx = i * 256 + tid;
        float4 v = xs[idx];
        f16x4 h; h.x = (f16)v.x; h.y = (f16)v.y; h.z = (f16)v.z; h.w = (f16)v.w;
        xd[idx] = h;
    }
    __syncthreads();

    const int cl = tid & 127;
    const int rh = tid >> 7;
    float acc[16];
#pragma unroll
    for (int r = 0; r < 16; ++r) acc[r] = 0.f;

#pragma unroll
    for (int kc = 0; kc < 2; ++kc) {
        f16x2 wv[32];
#pragma unroll
        for (int i = 0; i < 32; ++i) wv[i] = wih_s[kc * 32 + i][cl];
#pragma unroll
        for (int r = 0; r < 16; ++r) {
            const int row = rh * 16 + r;
#pragma unroll
            for (int m = 0; m < 8; ++m) {
                f16x8 h8 = *(const f16x8*)(&x_s[row][kc * 32 + 4 * m]);
                const f16x2* hp = (const f16x2*)&h8;
                acc[r] = fdot2f(wv[4 * m + 0], hp[0], acc[r]);
                acc[r] = fdot2f(wv[4 * m + 1], hp[1], acc[r]);
                acc[r] = fdot2f(wv[4 * m + 2], hp[2], acc[r]);
                acc[r] = fdot2f(wv[4 * m + 3], hp[3], acc[r]);
            }
        }
    }
#pragma unroll
    for (int r = 0; r < 16; ++r) {
        int row = r0 + rh * 16 + r;
        u[(size_t)row * H_DIM + c0 + cl] = (f16)acc[r];
    }
}

// ---------------------------------------------------------------------------
// Phase 2: split-K scan. One WG (512 threads) per batch element.
// Thread (kg = tid&7, cg = tid>>3) owns k-slice [kg*64, kg*64+64) for the
// 8 columns c = i*64+cg (i=0..7). W: cols i=0..6 + col7 pairs 0..3 in VGPRs
// (228 pairs); col7 pairs 4..31 in LDS (7 x b128). Per step each thread reads
// only its 128-byte h-slice (8 b128, bank-staggered via +16B padding), then
// the 8 column-partials are reduced across the 8 lanes of the group with a
// 3-round ds_swizzle butterfly on f16x2-packed sums. One barrier per step.
// ---------------------------------------------------------------------------
__device__ __forceinline__ f16x2 swz_add(f16x2 v, int imm_pattern_result) {
    // helper not used; kept inline below for imm constraints
    return v;
}

__global__ __launch_bounds__(512, 2)
void rnn_scan_kernel(const float* __restrict__ Wrec, f16* __restrict__ uhs) {
    const int tid = threadIdx.x;
    const int b = blockIdx.x;
    const int kg = tid & 7;        // k-slice: k in [kg*64, kg*64+64)
    const int cg = tid >> 3;       // 0..63; owns columns i*64+cg

    __shared__ __align__(16) f16x8 w4[7][512];        // col-7 pairs 4..31: 57344 B
    __shared__ __align__(16) f16 h_pad[2][8][72];     // 64 data + 8 pad per slice: 2304 B

    const int k0 = kg * 64;

    // ---- load W into registers (one-time; L2/L3-resident after first WG) ----
    f16x2 wreg[7][32];
#pragma unroll
    for (int i = 0; i < 7; ++i)
#pragma unroll
        for (int p = 0; p < 32; ++p) {
            float a = Wrec[(size_t)(k0 + 2 * p + 0) * H_DIM + i * 64 + cg];
            float c = Wrec[(size_t)(k0 + 2 * p + 1) * H_DIM + i * 64 + cg];
            f16x2 w; w.x = (f16)a; w.y = (f16)c;
            wreg[i][p] = w;
        }
    f16x8 w7pack;   // col 7 (c = 448+cg), k = k0..k0+7
#pragma unroll
    for (int e = 0; e < 8; ++e)
        w7pack[e] = (f16)Wrec[(size_t)(k0 + e) * H_DIM + 448 + cg];
    // col 7 k = k0+8 .. k0+63 -> LDS, w4[q][tid][e] = W[k0+8+8q+e][448+cg]
#pragma unroll
    for (int q = 0; q < 7; ++q) {
        f16x8 v;
#pragma unroll
        for (int e = 0; e < 8; ++e)
            v[e] = (f16)Wrec[(size_t)(k0 + 8 + 8 * q + e) * H_DIM + 448 + cg];
        w4[q][tid] = v;
    }
    if (tid < 576) ((f16*)h_pad)[tid] = (f16)0.f;   // zero h buffer 0 (incl pad)
    __syncthreads();

    // this thread's output column (and u column): c = kg*64 + cg
    const int c_own = k0 + cg;
    f16* io = uhs + (size_t)b * S_LEN * H_DIM + c_own;
    float h_prev = 0.f;
    float u_cur = (float)io[0];

    const f16* hb0 = &h_pad[0][kg][0];
    const f16* hb1 = &h_pad[1][kg][0];

    for (int t = 0; t < S_LEN; ++t) {
        // prefetch next u (scattered 2B loads within a 1KB row; latency hidden)
        f16 u_next = (f16)0.f;
        if (t + 1 < S_LEN) u_next = io[(size_t)(t + 1) * H_DIM];

        const f16* hb = (t & 1) ? hb1 : hb0;
        float acc[8];
#pragma unroll
        for (int i = 0; i < 8; ++i) acc[i] = 0.f;

#pragma unroll
        for (int g = 0; g < 8; ++g) {
            f16x8 hv = *(const f16x8*)(hb + g * 8);   // bank-staggered broadcast
            f16x8 w7v;
            if (g == 0) w7v = w7pack; else w7v = w4[g - 1][tid];
            const f16x2* hp = (const f16x2*)&hv;
            const f16x2* wp = (const f16x2*)&w7v;
#pragma unroll
            for (int p = 0; p < 4; ++p) {
                acc[0] = fdot2f(wreg[0][g * 4 + p], hp[p], acc[0]);
                acc[1] = fdot2f(wreg[1][g * 4 + p], hp[p], acc[1]);
                acc[2] = fdot2f(wreg[2][g * 4 + p], hp[p], acc[2]);
                acc[3] = fdot2f(wreg[3][g * 4 + p], hp[p], acc[3]);
                acc[4] = fdot2f(wreg[4][g * 4 + p], hp[p], acc[4]);
                acc[5] = fdot2f(wreg[5][g * 4 + p], hp[p], acc[5]);
                acc[6] = fdot2f(wreg[6][g * 4 + p], hp[p], acc[6]);
                acc[7] = fdot2f(wp[p], hp[p], acc[7]);
            }
        }

        // pack partials to f16x2 and butterfly-reduce over the 8 lanes (kg bits)
        f16x2 v0, v1, v2, v3;
        v0.x = (f16)acc[0]; v0.y = (f16)acc[1];
        v1.x = (f16)acc[2]; v1.y = (f16)acc[3];
        v2.x = (f16)acc[4]; v2.y = (f16)acc[5];
        v3.x = (f16)acc[6]; v3.y = (f16)acc[7];
#define SWZ_ADD(vv, IMM)                                                     \
        {                                                                    \
            int s_ = __builtin_amdgcn_ds_swizzle(__builtin_bit_cast(int, vv), IMM); \
            vv = vv + __builtin_bit_cast(f16x2, s_);                         \
        }
        SWZ_ADD(v0, 0x041F) SWZ_ADD(v1, 0x041F) SWZ_ADD(v2, 0x041F) SWZ_ADD(v3, 0x041F)
        SWZ_ADD(v0, 0x081F) SWZ_ADD(v1, 0x081F) SWZ_ADD(v2, 0x081F) SWZ_ADD(v3, 0x081F)
        SWZ_ADD(v0, 0x101F) SWZ_ADD(v1, 0x101F) SWZ_ADD(v2, 0x101F) SWZ_ADD(v3, 0x101F)
#undef SWZ_ADD

        // select own column's sum: i = kg -> pair kg>>1, half kg&1
        f16x2 t01 = (kg & 2) ? v1 : v0;
        f16x2 t23 = (kg & 2) ? v3 : v2;
        f16x2 tt  = (kg & 4) ? t23 : t01;
        float z = (float)((kg & 1) ? tt.y : tt.x) + u_cur;

        // tanh(z) = 1 - 2/(exp(2z)+1)
        float e2 = __expf(2.f * z);
        float r = 1.f - 2.f * __builtin_amdgcn_rcpf(e2 + 1.f);
        h_prev = 0.8f * h_prev + 0.2f * r;
        f16 hh = (f16)h_prev;

        h_pad[(t + 1) & 1][kg][cg] = hh;     // 2-way bank alias: free
        io[(size_t)t * H_DIM] = hh;          // hs[b][t][c] overwrites u slot
        u_cur = (float)u_next;
        __syncthreads();
    }
}

// ---------------------------------------------------------------------------
// Phase 3: out[row][o] = sum_k hs[row][k] * Who[k][o], K=512, O=64, fp32 out.
// ---------------------------------------------------------------------------
__global__ __launch_bounds__(256)
void out_gemm_kernel(const f16* __restrict__ hs, const float* __restrict__ Who,
                     float* __restrict__ out) {
    const int tid = threadIdx.x;
    const int r0 = blockIdx.x * 32;

    __shared__ __align__(16) f16x2 who_s[128][O_DIM];
    __shared__ __align__(16) f16x2 hs_s[32][128];

    const int o = tid & 63;
    const int rg = tid >> 6;

    float acc[8];
#pragma unroll
    for (int r = 0; r < 8; ++r) acc[r] = 0.f;

    for (int kc = 0; kc < 2; ++kc) {
        if (kc) __syncthreads();
#pragma unroll
        for (int i = 0; i < 32; ++i) {
            int idx = i * 256 + tid;
            int kp = idx >> 6;
            int oc = idx & 63;
            float w0 = Who[(size_t)(kc * 256 + 2 * kp + 0) * O_DIM + oc];
            float w1 = Who[(size_t)(kc * 256 + 2 * kp + 1) * O_DIM + oc];
            f16x2 w; w.x = (f16)w0; w.y = (f16)w1;
            who_s[kp][oc] = w;
        }
        f16x8* hd = (f16x8*)hs_s;
#pragma unroll
        for (int i = 0; i < 4; ++i) {
            int idx = i * 256 + tid;
            int r = idx >> 5;
            int m = idx & 31;
            f16x8 v = *(const f16x8*)(hs + (size_t)(r0 + r) * H_DIM + kc * 256 + m * 8);
            hd[idx] = v;
        }
        __syncthreads();

#pragma unroll
        for (int sc = 0; sc < 4; ++sc) {
            f16x2 wv[32];
#pragma unroll
            for (int i = 0; i < 32; ++i) wv[i] = who_s[sc * 32 + i][o];
#pragma unroll
            for (int r = 0; r < 8; ++r) {
                const int row = rg * 8 + r;
#pragma unroll
                for (int m = 0; m < 8; ++m) {
                    f16x8 h8 = *(const f16x8*)(&hs_s[row][sc * 32 + 4 * m]);
                    const f16x2* hp = (const f16x2*)&h8;
                    acc[r] = fdot2f(wv[4 * m + 0], hp[0], acc[r]);
                    acc[r] = fdot2f(wv[4 * m + 1], hp[1], acc[r]);
                    acc[r] = fdot2f(wv[4 * m + 2], hp[2], acc[r]);
                    acc[r] = fdot2f(wv[4 * m + 3], hp[3], acc[r]);
                }
            }
        }
    }
#pragma unroll
    for (int r = 0; r < 8; ++r) {
        int row = r0 + rg * 8 + r;
        out[(size_t)row * O_DIM + o] = acc[r];
    }
}

extern "C" void kernel_launch(void* const* d_in, const int* in_sizes, int n_in,
                              void* d_out, int out_size, void* d_ws, size_t ws_size,
                              hipStream_t stream) {
    const float* x    = (const float*)d_in[0];   // [64][2048][128]
    const float* Wih  = (const float*)d_in[1];   // [128][512]
    const float* Wrec = (const float*)d_in[2];   // [512][512]
    const float* Who  = (const float*)d_in[3];   // [512][64]
    float* out = (float*)d_out;                  // [64][2048][64]
    f16* uhs = (f16*)d_ws;                       // 128 MB: u, then hs in-place

    const int R = BATCH * S_LEN;

    u_gemm_kernel<<<dim3(R / 32, H_DIM / 128), 256, 0, stream>>>(x, Wih, uhs);
    rnn_scan_kernel<<<dim3(BATCH), 512, 0, stream>>>(Wrec, uhs);
    out_gemm_kernel<<<dim3(R / 32), 256, 0, stream>>>(uhs, Who, out);
}